// Round 4
// baseline (55.270 us; speedup 1.0000x reference)
//
#include <hip/hip_runtime.h>
#include <hip/hip_bf16.h>
#include <math.h>

// Problem: x (64, 2, 512, 512) f32. x0 = x[:,0] -> (64,512,512).
// n[v] = sqrt(sum_{b,f} x0[b,v,f]^2)
// out[b,i,j] = (sum_f x0[b,i,f]*x0[b,j,f]) / (n[i]*n[j])

#define BATCH 64
#define VDIM 512
#define FDIM 512
#define XBS (2 * VDIM * FDIM)      // x batch stride in floats (T=2)
#define OBS (VDIM * VDIM)          // out batch stride in floats

typedef __bf16 bf16x8 __attribute__((ext_vector_type(8)));
typedef __bf16 bf16x4 __attribute__((ext_vector_type(4)));
typedef float f32x4 __attribute__((ext_vector_type(4)));

#define BM 128
#define BK 64                      // bf16 elems per K-step
#define NKT (FDIM / BK)            // 8 K-steps

// ws layout: [0, 33554432): bf16 x0 copy (64*512*512); then f32 inv_n[512]
#define INVN_OFF 33554432

// global -> LDS direct copy, 16B per lane (dest is wave-uniform base + lane*16)
#define GLL16(g, l)                                                          \
    __builtin_amdgcn_global_load_lds(                                        \
        (const __attribute__((address_space(1))) void*)(g),                  \
        (__attribute__((address_space(3))) void*)(l), 16, 0, 0)

// ---------------- fused norm + bf16-convert kernel: one block per v ----------------
__global__ __launch_bounds__(512) void cvt_norm_kernel(const float* __restrict__ x,
                                                       __bf16* __restrict__ xb,
                                                       float* __restrict__ inv_n) {
    const int v = blockIdx.x;
    const int tid = threadIdx.x;
    float s = 0.f;
    const float4* xf4 = (const float4*)x;
    // 64 batches x 128 float4 per (b, v) row
    for (int c = tid; c < 8192; c += 512) {
        int b = c >> 7;
        int f4 = c & 127;
        float4 d = xf4[(size_t)b * (XBS / 4) + (size_t)v * (FDIM / 4) + f4];
        s += d.x * d.x + d.y * d.y + d.z * d.z + d.w * d.w;
        bf16x4 p;
        p[0] = (__bf16)d.x; p[1] = (__bf16)d.y; p[2] = (__bf16)d.z; p[3] = (__bf16)d.w;
        *(bf16x4*)&xb[(size_t)b * (VDIM * FDIM) + (size_t)v * FDIM + f4 * 4] = p;
    }
    #pragma unroll
    for (int off = 32; off > 0; off >>= 1) s += __shfl_down(s, off, 64);
    __shared__ float partial[8];
    if ((tid & 63) == 0) partial[tid >> 6] = s;
    __syncthreads();
    if (tid == 0) {
        float t = 0.f;
        #pragma unroll
        for (int w = 0; w < 8; ++w) t += partial[w];
        inv_n[v] = 1.0f / sqrtf(t);
    }
}

// ---------------- gram kernel: dbuf LDS + counted vmcnt + raw barriers ----------------
__global__ __launch_bounds__(256) void gram_kernel(const __bf16* __restrict__ xb,
                                                   const float* __restrict__ inv_n,
                                                   float* __restrict__ out) {
    __shared__ __bf16 As[2][BM * BK];   // 2 x 16 KB, linear (+XOR swizzle via src)
    __shared__ __bf16 Bs[2][BM * BK];

    // 64 batches x 16 tiles = 1024 blocks
    // XCD chunked swizzle: 1024 / 8 = 128 contiguous logical wgs per XCD (8 batches)
    const int bid = blockIdx.x;
    const int wg = (bid & 7) * 128 + (bid >> 3);
    const int batch = wg >> 4;
    const int tile = wg & 15;
    const int ti = tile >> 2;
    const int tj = tile & 3;

    const __bf16* xbb = xb + (size_t)batch * (VDIM * FDIM);
    const int tid = threadIdx.x;
    const int lane = tid & 63;
    const int wave = tid >> 6;     // 0..3
    const int wr = wave >> 1;      // 0..1
    const int wc = wave & 1;       // 0..1

    // ---- staging addresses (constant per thread; k advances via imm offset) ----
    // chunk c = it*256 + tid in [0,1024): row = c>>3, cc = c&7
    // LDS chunk (row,cc) holds global 16B-chunk (row, cc ^ (row&7))  [both-sides XOR]
    const __bf16* gA[4];
    const __bf16* gB[4];
    int ldsoff[4];                 // element offset within one buffer
    #pragma unroll
    for (int it = 0; it < 4; ++it) {
        int c = it * 256 + tid;
        int row = c >> 3;
        int cs = (c & 7) ^ (row & 7);
        gA[it] = xbb + (size_t)(ti * BM + row) * FDIM + cs * 8;
        gB[it] = xbb + (size_t)(tj * BM + row) * FDIM + cs * 8;
        ldsoff[it] = c * 8;
    }

    // ---- fragment LDS byte offsets (constant per lane; within one buffer) ----
    // element (r, k=ks*32+(lane>>4)*8) lives at LDS chunk (r, (ks*4+(lane>>4)) ^ (r&7))
    int offA[2][4], offB[2][4];
    #pragma unroll
    for (int ks = 0; ks < 2; ++ks) {
        #pragma unroll
        for (int m = 0; m < 4; ++m) {
            int rA = wr * 64 + m * 16 + (lane & 15);
            int rB = wc * 64 + m * 16 + (lane & 15);
            int gch = ks * 4 + (lane >> 4);
            offA[ks][m] = rA * (BK * 2) + ((gch ^ (rA & 7)) * 16);
            offB[ks][m] = rB * (BK * 2) + ((gch ^ (rB & 7)) * 16);
        }
    }

    f32x4 acc[4][4];
    #pragma unroll
    for (int m = 0; m < 4; ++m)
        #pragma unroll
        for (int n = 0; n < 4; ++n)
            acc[m][n] = (f32x4){0.f, 0.f, 0.f, 0.f};

    // ---- prologue: stage tile 0 into buf 0 ----
    #pragma unroll
    for (int it = 0; it < 4; ++it) {
        GLL16(gA[it], &As[0][ldsoff[it]]);
        GLL16(gB[it], &Bs[0][ldsoff[it]]);
    }

    // ---- main loop: tile t in buf (t&1); stage t+1 into buf ((t+1)&1) ----
    #pragma unroll
    for (int t = 0; t < NKT; ++t) {
        if (t < NKT - 1) {
            const int nb = (t + 1) & 1;
            #pragma unroll
            for (int it = 0; it < 4; ++it) {
                GLL16(gA[it] + (t + 1) * BK, &As[nb][ldsoff[it]]);
                GLL16(gB[it] + (t + 1) * BK, &Bs[nb][ldsoff[it]]);
            }
            asm volatile("s_waitcnt vmcnt(8)" ::: "memory");
        } else {
            asm volatile("s_waitcnt vmcnt(0)" ::: "memory");
        }
        __builtin_amdgcn_s_barrier();   // tile t fully in LDS for all waves

        const char* Ab = (const char*)&As[t & 1][0];
        const char* Bb = (const char*)&Bs[t & 1][0];
        #pragma unroll
        for (int ks = 0; ks < 2; ++ks) {
            bf16x8 af[4], bfr[4];
            #pragma unroll
            for (int m = 0; m < 4; ++m) {
                af[m]  = *(const bf16x8*)(Ab + offA[ks][m]);
                bfr[m] = *(const bf16x8*)(Bb + offB[ks][m]);
            }
            #pragma unroll
            for (int m = 0; m < 4; ++m)
                #pragma unroll
                for (int n = 0; n < 4; ++n)
                    acc[m][n] = __builtin_amdgcn_mfma_f32_16x16x32_bf16(af[m], bfr[n], acc[m][n], 0, 0, 0);
        }
        asm volatile("s_waitcnt lgkmcnt(0)" ::: "memory");  // my ds_reads retired
        __builtin_amdgcn_s_barrier();   // safe to overwrite buf (t&1) next iter
    }

    // ---- epilogue: scale by inv_n[i]*inv_n[j], store ----
    const int rowbase = ti * BM + wr * 64;
    const int colbase = tj * BM + wc * 64;
    float* ob = out + (size_t)batch * OBS;

    float si[16];
    #pragma unroll
    for (int m = 0; m < 4; ++m)
        #pragma unroll
        for (int q = 0; q < 4; ++q)
            si[m * 4 + q] = inv_n[rowbase + m * 16 + (lane >> 4) * 4 + q];

    #pragma unroll
    for (int n = 0; n < 4; ++n) {
        int j = colbase + n * 16 + (lane & 15);
        float sj = inv_n[j];
        #pragma unroll
        for (int m = 0; m < 4; ++m) {
            #pragma unroll
            for (int q = 0; q < 4; ++q) {
                int i = rowbase + m * 16 + (lane >> 4) * 4 + q;
                ob[(size_t)i * VDIM + j] = acc[m][n][q] * si[m * 4 + q] * sj;
            }
        }
    }
}

extern "C" void kernel_launch(void* const* d_in, const int* in_sizes, int n_in,
                              void* d_out, int out_size, void* d_ws, size_t ws_size,
                              hipStream_t stream) {
    const float* x = (const float*)d_in[0];
    float* out = (float*)d_out;
    __bf16* xbf = (__bf16*)d_ws;
    float* inv_n = (float*)((char*)d_ws + INVN_OFF);

    cvt_norm_kernel<<<VDIM, 512, 0, stream>>>(x, xbf, inv_n);
    gram_kernel<<<BATCH * 16, 256, 0, stream>>>(xbf, inv_n, out);
}

// Round 5
// 52.378 us; speedup vs baseline: 1.0552x; 1.0552x over previous
//
#include <hip/hip_runtime.h>
#include <hip/hip_bf16.h>
#include <math.h>

// Problem: x (64, 2, 512, 512) f32. x0 = x[:,0] -> (64,512,512).
// n[v] = sqrt(sum_{b,f} x0[b,v,f]^2)
// out[b,i,j] = (sum_f x0[b,i,f]*x0[b,j,f]) / (n[i]*n[j])

#define BATCH 64
#define VDIM 512
#define FDIM 512
#define XBS (2 * VDIM * FDIM)      // x batch stride in floats (T=2)
#define OBS (VDIM * VDIM)          // out batch stride in floats

typedef __bf16 bf16x8 __attribute__((ext_vector_type(8)));
typedef __bf16 bf16x4 __attribute__((ext_vector_type(4)));
typedef float f32x4 __attribute__((ext_vector_type(4)));

// ws layout: [0, 33554432): bf16 x0 copy (64*512*512); then f32 inv_n[512]
#define INVN_OFF 33554432

// global -> LDS direct copy, 16B per lane (dest is wave-uniform base + lane*16)
#define GLL16(g, l)                                                          \
    __builtin_amdgcn_global_load_lds(                                        \
        (const __attribute__((address_space(1))) void*)(g),                  \
        (__attribute__((address_space(3))) void*)(l), 16, 0, 0)

// ---------------- fused norm + bf16-convert kernel: one block per v ----------------
__global__ __launch_bounds__(512) void cvt_norm_kernel(const float* __restrict__ x,
                                                       __bf16* __restrict__ xb,
                                                       float* __restrict__ inv_n) {
    const int v = blockIdx.x;
    const int tid = threadIdx.x;
    float s = 0.f;
    const float4* xf4 = (const float4*)x;
    for (int c = tid; c < 8192; c += 512) {
        int b = c >> 7;
        int f4 = c & 127;
        float4 d = xf4[(size_t)b * (XBS / 4) + (size_t)v * (FDIM / 4) + f4];
        s += d.x * d.x + d.y * d.y + d.z * d.z + d.w * d.w;
        bf16x4 p;
        p[0] = (__bf16)d.x; p[1] = (__bf16)d.y; p[2] = (__bf16)d.z; p[3] = (__bf16)d.w;
        *(bf16x4*)&xb[(size_t)b * (VDIM * FDIM) + (size_t)v * FDIM + f4 * 4] = p;
    }
    #pragma unroll
    for (int off = 32; off > 0; off >>= 1) s += __shfl_down(s, off, 64);
    __shared__ float partial[8];
    if ((tid & 63) == 0) partial[tid >> 6] = s;
    __syncthreads();
    if (tid == 0) {
        float t = 0.f;
        #pragma unroll
        for (int w = 0; w < 8; ++w) t += partial[w];
        inv_n[v] = 1.0f / sqrtf(t);
    }
}

// ---------------- gram kernel: 256^2 tile, 8 waves, 4-phase pipelined, dbuf ----------------
// LDS: As/Bs 2 bufs x 256x64 bf16 = 128 KB total. Half-tile = 128 rows x 64 K (16 KB).
// Stage slots per kt (verified vs region-seal barriers):
//   P1: Ah1(kt+1)   [A-half1 of other buf last read at prev iter P3]
//   P3: Bh0(kt+2)   [B of this buf fully read after P2]
//   P4: Bh1(kt+2), Ah0(kt+2)  [A-half0 of this buf read after P3]
//   vmcnt(6) at P4: 3 half-tiles (6 loads) stay in flight; kt+1 guaranteed landed.
__global__ __launch_bounds__(512, 2) void gram_kernel(const __bf16* __restrict__ xb,
                                                      const float* __restrict__ inv_n,
                                                      float* __restrict__ out) {
    __shared__ __bf16 As[2][16384];   // [buf][256*64]
    __shared__ __bf16 Bs[2][16384];

    // 64 batches x 4 tiles (2x2 of 256^2) = 256 blocks; XCD chunked swizzle (256%8==0)
    const int bid = blockIdx.x;
    const int wg = (bid & 7) * 32 + (bid >> 3);
    const int batch = wg >> 2;
    const int tile = wg & 3;
    const int tr = tile >> 1;
    const int tc = tile & 1;

    const __bf16* xbb = xb + (size_t)batch * (VDIM * FDIM);
    const int tid = threadIdx.x;
    const int lane = tid & 63;
    const int wave = tid >> 6;     // 0..7
    const int wr = wave >> 2;      // 0..1
    const int wc = wave & 3;       // 0..3

    // ---- staging addresses ----
    // chunk c = j*512 + tid; row_in_half = c>>3 = j*64 + (tid>>3); cc = c&7 = tid&7
    // LDS chunk (row,cc) holds global chunk (row, cc ^ (row&7))  [both-sides XOR]
    const int r0 = tid >> 3;
    const int cs = (tid & 7) ^ (r0 & 7);
    const __bf16* pA[2][2];
    const __bf16* pB[2][2];
    #pragma unroll
    for (int h = 0; h < 2; ++h)
        #pragma unroll
        for (int j = 0; j < 2; ++j) {
            pA[h][j] = xbb + (size_t)(tr * 256 + h * 128 + j * 64 + r0) * FDIM + cs * 8;
            pB[h][j] = xbb + (size_t)(tc * 256 + h * 128 + j * 64 + r0) * FDIM + cs * 8;
        }

#define STAGE_A(KT, H) do {                                                      \
        GLL16(pA[H][0] + (KT) * 64, &As[(KT) & 1][((H) * 1024 + tid) * 8]);      \
        GLL16(pA[H][1] + (KT) * 64, &As[(KT) & 1][((H) * 1024 + 512 + tid) * 8]);\
    } while (0)
#define STAGE_B(KT, H) do {                                                      \
        GLL16(pB[H][0] + (KT) * 64, &Bs[(KT) & 1][((H) * 1024 + tid) * 8]);      \
        GLL16(pB[H][1] + (KT) * 64, &Bs[(KT) & 1][((H) * 1024 + 512 + tid) * 8]);\
    } while (0)

    // ---- fragment LDS byte offsets ----
    // element (r, k=ks*32+(lane>>4)*8): chunk g = ks*4+(lane>>4); swizzled gs = g^(r&7);
    // r&7 == lane&7 for all frags; ks toggles byte-bit 6 (gs^4 -> ^64 bytes).
    const int gs0 = (lane >> 4) ^ (lane & 7);
    const int abase = (wr * 128 + (lane & 15)) * 128 + gs0 * 16;
    const int bbase = (wc * 64 + (lane & 15)) * 128 + gs0 * 16;

    f32x4 acc[8][4];
    #pragma unroll
    for (int m = 0; m < 8; ++m)
        #pragma unroll
        for (int n = 0; n < 4; ++n)
            acc[m][n] = (f32x4){0.f, 0.f, 0.f, 0.f};

    // ---- prologue: kt0 complete + kt1 {Bh0,Bh1,Ah0}; Ah1(1) comes at kt0's P1 ----
    STAGE_A(0, 0); STAGE_A(0, 1); STAGE_B(0, 0); STAGE_B(0, 1);
    STAGE_B(1, 0); STAGE_B(1, 1); STAGE_A(1, 0);
    asm volatile("s_waitcnt vmcnt(6)" ::: "memory");   // kt0's 8 loads landed
    asm volatile("s_barrier" ::: "memory");

    #pragma unroll
    for (int kt = 0; kt < 8; ++kt) {
        const char* Ab = (const char*)&As[kt & 1][0];
        const char* Bb = (const char*)&Bs[kt & 1][0];
        bf16x8 af[2][4], bfl[2][2], bgh[2][2];

        // ---- P1: ds A[mh0] (8) + B[nh0] (4); stage Ah1(kt+1); MFMA quad (mh0, n0-1) ----
        #pragma unroll
        for (int ks = 0; ks < 2; ++ks) {
            #pragma unroll
            for (int m = 0; m < 4; ++m)
                af[ks][m] = *(const bf16x8*)(Ab + ((abase + m * 2048) ^ (ks * 64)));
            #pragma unroll
            for (int n = 0; n < 2; ++n)
                bfl[ks][n] = *(const bf16x8*)(Bb + ((bbase + n * 2048) ^ (ks * 64)));
        }
        if (kt + 1 < 8) STAGE_A(kt + 1, 1);
        asm volatile("s_barrier" ::: "memory");
        __builtin_amdgcn_s_setprio(1);
        #pragma unroll
        for (int ks = 0; ks < 2; ++ks)
            #pragma unroll
            for (int m = 0; m < 4; ++m)
                #pragma unroll
                for (int n = 0; n < 2; ++n)
                    acc[m][n] = __builtin_amdgcn_mfma_f32_16x16x32_bf16(af[ks][m], bfl[ks][n], acc[m][n], 0, 0, 0);
        __builtin_amdgcn_s_setprio(0);
        asm volatile("s_barrier" ::: "memory");

        // ---- P2: ds B[nh1] (4); MFMA quad (mh0, n2-3) ----
        #pragma unroll
        for (int ks = 0; ks < 2; ++ks)
            #pragma unroll
            for (int n = 0; n < 2; ++n)
                bgh[ks][n] = *(const bf16x8*)(Bb + ((bbase + (2 + n) * 2048) ^ (ks * 64)));
        asm volatile("s_barrier" ::: "memory");
        __builtin_amdgcn_s_setprio(1);
        #pragma unroll
        for (int ks = 0; ks < 2; ++ks)
            #pragma unroll
            for (int m = 0; m < 4; ++m)
                #pragma unroll
                for (int n = 0; n < 2; ++n)
                    acc[m][2 + n] = __builtin_amdgcn_mfma_f32_16x16x32_bf16(af[ks][m], bgh[ks][n], acc[m][2 + n], 0, 0, 0);
        __builtin_amdgcn_s_setprio(0);
        asm volatile("s_barrier" ::: "memory");

        // ---- P3: ds A[mh1] (8); stage Bh0(kt+2); MFMA quad (mh1, n2-3) ----
        #pragma unroll
        for (int ks = 0; ks < 2; ++ks)
            #pragma unroll
            for (int m = 0; m < 4; ++m)
                af[ks][m] = *(const bf16x8*)(Ab + ((abase + 8192 + m * 2048) ^ (ks * 64)));
        if (kt + 2 < 8) STAGE_B(kt + 2, 0);
        asm volatile("s_barrier" ::: "memory");
        __builtin_amdgcn_s_setprio(1);
        #pragma unroll
        for (int ks = 0; ks < 2; ++ks)
            #pragma unroll
            for (int m = 0; m < 4; ++m)
                #pragma unroll
                for (int n = 0; n < 2; ++n)
                    acc[4 + m][2 + n] = __builtin_amdgcn_mfma_f32_16x16x32_bf16(af[ks][m], bgh[ks][n], acc[4 + m][2 + n], 0, 0, 0);
        __builtin_amdgcn_s_setprio(0);
        asm volatile("s_barrier" ::: "memory");

        // ---- P4: stage Bh1(kt+2)+Ah0(kt+2); vmcnt(6); MFMA quad (mh1, n0-1) ----
        if (kt + 2 < 8) { STAGE_B(kt + 2, 1); STAGE_A(kt + 2, 0); }
        if (kt <= 5)
            asm volatile("s_waitcnt vmcnt(6)" ::: "memory");   // kt+1 fully landed
        else
            asm volatile("s_waitcnt vmcnt(0)" ::: "memory");
        asm volatile("s_barrier" ::: "memory");
        __builtin_amdgcn_s_setprio(1);
        #pragma unroll
        for (int ks = 0; ks < 2; ++ks)
            #pragma unroll
            for (int m = 0; m < 4; ++m)
                #pragma unroll
                for (int n = 0; n < 2; ++n)
                    acc[4 + m][n] = __builtin_amdgcn_mfma_f32_16x16x32_bf16(af[ks][m], bfl[ks][n], acc[4 + m][n], 0, 0, 0);
        __builtin_amdgcn_s_setprio(0);
        asm volatile("s_barrier" ::: "memory");
    }

    // ---- epilogue: scale by inv_n[i]*inv_n[j], store ----
    const int rowbase = tr * 256 + wr * 128;
    const int colbase = tc * 256 + wc * 64;
    float* ob = out + (size_t)batch * OBS;

    float si[32];
    #pragma unroll
    for (int m = 0; m < 8; ++m)
        #pragma unroll
        for (int q = 0; q < 4; ++q)
            si[m * 4 + q] = inv_n[rowbase + m * 16 + (lane >> 4) * 4 + q];

    #pragma unroll
    for (int n = 0; n < 4; ++n) {
        int j = colbase + n * 16 + (lane & 15);
        float sj = inv_n[j];
        #pragma unroll
        for (int m = 0; m < 8; ++m) {
            #pragma unroll
            for (int q = 0; q < 4; ++q) {
                int i = rowbase + m * 16 + (lane >> 4) * 4 + q;
                ob[(size_t)i * VDIM + j] = acc[m][n][q] * si[m * 4 + q] * sj;
            }
        }
    }
#undef STAGE_A
#undef STAGE_B
}

extern "C" void kernel_launch(void* const* d_in, const int* in_sizes, int n_in,
                              void* d_out, int out_size, void* d_ws, size_t ws_size,
                              hipStream_t stream) {
    const float* x = (const float*)d_in[0];
    float* out = (float*)d_out;
    __bf16* xbf = (__bf16*)d_ws;
    float* inv_n = (float*)((char*)d_ws + INVN_OFF);

    cvt_norm_kernel<<<VDIM, 512, 0, stream>>>(x, xbf, inv_n);
    gram_kernel<<<BATCH * 4, 512, 0, stream>>>(xbf, inv_n, out);
}